// Round 1
// baseline (413.494 us; speedup 1.0000x reference)
//
#include <hip/hip_runtime.h>

// HistogramNd: values [N,3] f32, weights [N] f32 -> hist [64*64*64] f32 + oob scalar.
// d_out = [hist (out_size-1 floats), oob (1 float)].

__global__ void __launch_bounds__(256)
init_out_kernel(const float* __restrict__ hist_sum,
                const float* __restrict__ oob_sum,
                float* __restrict__ out, int hist_n) {
    int i = blockIdx.x * blockDim.x + threadIdx.x;
    if (i < hist_n) out[i] = hist_sum[i];
    if (i == 0) out[hist_n] = oob_sum[0];
}

__global__ void __launch_bounds__(256)
hist_kernel(const float4* __restrict__ vals4,   // N*3/4 float4s
            const float4* __restrict__ w4,      // N/4 float4s
            const float* __restrict__ rmin,
            const float* __restrict__ rmax,
            const int* __restrict__ nbins,
            const int* __restrict__ stride,
            float* __restrict__ out, int n4, int hist_n) {
    int i = blockIdx.x * blockDim.x + threadIdx.x;
    float oob = 0.f;
    if (i < n4) {
        // uniform params -> scalar loads
        const float lo0 = rmin[0], lo1 = rmin[1], lo2 = rmin[2];
        const float hi0 = rmax[0], hi1 = rmax[1], hi2 = rmax[2];
        const int   nb0 = nbins[0], nb1 = nbins[1], nb2 = nbins[2];
        const int   s0  = stride[0], s1 = stride[1], s2 = stride[2];

        // 4 points = 12 floats of values + 4 weights
        const float4 a = vals4[3 * (long)i + 0];
        const float4 b = vals4[3 * (long)i + 1];
        const float4 c = vals4[3 * (long)i + 2];
        const float4 w = w4[i];

        const float px[4][3] = {{a.x, a.y, a.z},
                                {a.w, b.x, b.y},
                                {b.z, b.w, c.x},
                                {c.y, c.z, c.w}};
        const float ws[4] = {w.x, w.y, w.z, w.w};

#pragma unroll
        for (int p = 0; p < 4; ++p) {
            // exactly the reference math: floor((v-lo)/(hi-lo)*nb) -> int32
            const int b0 = (int)floorf((px[p][0] - lo0) / (hi0 - lo0) * (float)nb0);
            const int b1 = (int)floorf((px[p][1] - lo1) / (hi1 - lo1) * (float)nb1);
            const int b2 = (int)floorf((px[p][2] - lo2) / (hi2 - lo2) * (float)nb2);
            const bool valid = (b0 >= 0) & (b0 < nb0) &
                               (b1 >= 0) & (b1 < nb1) &
                               (b2 >= 0) & (b2 < nb2);
            if (valid) {
                atomicAdd(&out[b0 * s0 + b1 * s1 + b2 * s2], ws[p]);
            } else {
                oob += ws[p];
            }
        }
    }
    // wave-level reduction of oob, one atomic per wave (skipped when zero)
#pragma unroll
    for (int o = 32; o > 0; o >>= 1) oob += __shfl_down(oob, o);
    if ((threadIdx.x & 63) == 0 && oob != 0.f) atomicAdd(&out[hist_n], oob);
}

extern "C" void kernel_launch(void* const* d_in, const int* in_sizes, int n_in,
                              void* d_out, int out_size, void* d_ws, size_t ws_size,
                              hipStream_t stream) {
    // input order: values, weights, hist_sum, oob_sum, range_min, range_max, n_bins, stride
    const float* values   = (const float*)d_in[0];
    const float* weights  = (const float*)d_in[1];
    const float* hist_sum = (const float*)d_in[2];
    const float* oob_sum  = (const float*)d_in[3];
    const float* rmin     = (const float*)d_in[4];
    const float* rmax     = (const float*)d_in[5];
    const int*   nbins    = (const int*)d_in[6];
    const int*   stride_p = (const int*)d_in[7];

    const int N      = in_sizes[1];      // number of points (weights length)
    const int hist_n = out_size - 1;     // 64*64*64
    const int n4     = N / 4;            // points processed 4 per thread (N % 4 == 0)

    // 1) initialize output (hist_sum copy + oob scalar) — every call
    {
        const int threads = 256;
        const int blocks  = (hist_n + 1 + threads - 1) / threads;
        init_out_kernel<<<blocks, threads, 0, stream>>>(hist_sum, oob_sum,
                                                        (float*)d_out, hist_n);
    }
    // 2) scatter-add histogram
    {
        const int threads = 256;
        const int blocks  = (n4 + threads - 1) / threads;
        hist_kernel<<<blocks, threads, 0, stream>>>(
            (const float4*)values, (const float4*)weights,
            rmin, rmax, nbins, stride_p,
            (float*)d_out, n4, hist_n);
    }
}

// Round 2
// 412.824 us; speedup vs baseline: 1.0016x; 1.0016x over previous
//
#include <hip/hip_runtime.h>

// HistogramNd: values [N,3] f32, weights [N] f32 -> hist [64*64*64] f32 + oob scalar.
// d_out = [hist (out_size-1 floats), oob (1 float)].

__global__ void __launch_bounds__(256)
init_out_kernel(const float* __restrict__ hist_sum,
                const float* __restrict__ oob_sum,
                float* __restrict__ out, int hist_n) {
    int i = blockIdx.x * blockDim.x + threadIdx.x;
    if (i < hist_n) out[i] = hist_sum[i];
    if (i == 0) out[hist_n] = oob_sum[0];
}

__global__ void __launch_bounds__(256)
hist_kernel(const float4* __restrict__ vals4,   // N*3/4 float4s
            const float4* __restrict__ w4,      // N/4 float4s
            const float* __restrict__ rmin,
            const float* __restrict__ rmax,
            const int* __restrict__ nbins,
            const int* __restrict__ stride,
            float* __restrict__ out, int n4, int hist_n) {
    int i = blockIdx.x * blockDim.x + threadIdx.x;
    float oob = 0.f;
    if (i < n4) {
        // uniform params -> scalar loads
        const float lo0 = rmin[0], lo1 = rmin[1], lo2 = rmin[2];
        const float hi0 = rmax[0], hi1 = rmax[1], hi2 = rmax[2];
        const int   nb0 = nbins[0], nb1 = nbins[1], nb2 = nbins[2];
        const int   s0  = stride[0], s1 = stride[1], s2 = stride[2];

        // 4 points = 12 floats of values + 4 weights
        const float4 a = vals4[3 * (long)i + 0];
        const float4 b = vals4[3 * (long)i + 1];
        const float4 c = vals4[3 * (long)i + 2];
        const float4 w = w4[i];

        const float px[4][3] = {{a.x, a.y, a.z},
                                {a.w, b.x, b.y},
                                {b.z, b.w, c.x},
                                {c.y, c.z, c.w}};
        const float ws[4] = {w.x, w.y, w.z, w.w};

#pragma unroll
        for (int p = 0; p < 4; ++p) {
            // exactly the reference math: floor((v-lo)/(hi-lo)*nb) -> int32
            const int b0 = (int)floorf((px[p][0] - lo0) / (hi0 - lo0) * (float)nb0);
            const int b1 = (int)floorf((px[p][1] - lo1) / (hi1 - lo1) * (float)nb1);
            const int b2 = (int)floorf((px[p][2] - lo2) / (hi2 - lo2) * (float)nb2);
            const bool valid = (b0 >= 0) & (b0 < nb0) &
                               (b1 >= 0) & (b1 < nb1) &
                               (b2 >= 0) & (b2 < nb2);
            if (valid) {
                // fire-and-forget HW f32 atomic (global_atomic_add_f32),
                // NOT the default CAS loop atomicAdd() lowers to.
                unsafeAtomicAdd(&out[b0 * s0 + b1 * s1 + b2 * s2], ws[p]);
            } else {
                oob += ws[p];
            }
        }
    }
    // wave-level reduction of oob, one atomic per wave (skipped when zero)
#pragma unroll
    for (int o = 32; o > 0; o >>= 1) oob += __shfl_down(oob, o);
    if ((threadIdx.x & 63) == 0 && oob != 0.f) unsafeAtomicAdd(&out[hist_n], oob);
}

extern "C" void kernel_launch(void* const* d_in, const int* in_sizes, int n_in,
                              void* d_out, int out_size, void* d_ws, size_t ws_size,
                              hipStream_t stream) {
    // input order: values, weights, hist_sum, oob_sum, range_min, range_max, n_bins, stride
    const float* values   = (const float*)d_in[0];
    const float* weights  = (const float*)d_in[1];
    const float* hist_sum = (const float*)d_in[2];
    const float* oob_sum  = (const float*)d_in[3];
    const float* rmin     = (const float*)d_in[4];
    const float* rmax     = (const float*)d_in[5];
    const int*   nbins    = (const int*)d_in[6];
    const int*   stride_p = (const int*)d_in[7];

    const int N      = in_sizes[1];      // number of points (weights length)
    const int hist_n = out_size - 1;     // 64*64*64
    const int n4     = N / 4;            // points processed 4 per thread (N % 4 == 0)

    // 1) initialize output (hist_sum copy + oob scalar) — every call
    {
        const int threads = 256;
        const int blocks  = (hist_n + 1 + threads - 1) / threads;
        init_out_kernel<<<blocks, threads, 0, stream>>>(hist_sum, oob_sum,
                                                        (float*)d_out, hist_n);
    }
    // 2) scatter-add histogram
    {
        const int threads = 256;
        const int blocks  = (n4 + threads - 1) / threads;
        hist_kernel<<<blocks, threads, 0, stream>>>(
            (const float4*)values, (const float4*)weights,
            rmin, rmax, nbins, stride_p,
            (float*)d_out, n4, hist_n);
    }
}